// Round 17
// baseline (438.336 us; speedup 1.0000x reference)
//
#include <hip/hip_runtime.h>
#include <type_traits>

#define DEV __device__ __forceinline__

typedef __attribute__((ext_vector_type(4))) float f32x4;
typedef __attribute__((ext_vector_type(8))) __bf16 bf16x8;
typedef __attribute__((ext_vector_type(8))) short s16x8;
typedef unsigned int u32;
typedef unsigned short u16;

DEV u16 f2bf(float f) {
  u32 u = __builtin_bit_cast(u32, f);
  u32 r = u + 0x7FFFu + ((u >> 16) & 1u);
  return (u16)(r >> 16);
}
DEV float bf2f(u16 h) {
  u32 u = ((u32)h) << 16;
  return __builtin_bit_cast(float, u);
}

// ---- MFMA wrapper: SFINAE over builtin operand type (bf16x8 vs s16x8) ----
template <typename A>
DEV auto mfma_sel(A a, A b, f32x4 c, int)
    -> decltype(__builtin_amdgcn_mfma_f32_16x16x32_bf16(a, b, c, 0, 0, 0)) {
  return __builtin_amdgcn_mfma_f32_16x16x32_bf16(a, b, c, 0, 0, 0);
}
template <typename A>
DEV f32x4 mfma_sel(A a, A b, f32x4 c, long) {
  using O = typename std::conditional<std::is_same<A, bf16x8>::value, s16x8, bf16x8>::type;
  return __builtin_amdgcn_mfma_f32_16x16x32_bf16(
      __builtin_bit_cast(O, a), __builtin_bit_cast(O, b), c, 0, 0, 0);
}
DEV f32x4 MFMA16(bf16x8 a, bf16x8 b, f32x4 c) { return mfma_sel(a, b, c, 0); }

DEV void gload_lds16(const void* g, void* l) {
  __builtin_amdgcn_global_load_lds(
      (__attribute__((address_space(1))) void*)(g),
      (__attribute__((address_space(3))) void*)(l), 16, 0, 0);
}

// ---------------- fused prologue: cvt x / w_qkv / w_o to bf16 + cos/sin table ----------------
// grid = 2048 (x) + 768 (w_qkv) + 256 (w_o) + 512 (cst) = 3584 blocks x 256 threads.
__global__ __launch_bounds__(256) void prologue(const float* __restrict__ x,
                                                const float* __restrict__ wq,
                                                const float* __restrict__ wo,
                                                const float* __restrict__ freqs,
                                                u16* __restrict__ x_bf,
                                                u16* __restrict__ wq_bf,
                                                u16* __restrict__ wo_bf,
                                                float2* __restrict__ cst) {
  const int b = blockIdx.x;
  auto cvt_seg = [&](const float* in, u16* out, int i, int n4, int stride) {
    for (; i < n4; i += stride) {
      const float4 v = ((const float4*)in)[i];
      ushort4 o;
      o.x = f2bf(v.x); o.y = f2bf(v.y); o.z = f2bf(v.z); o.w = f2bf(v.w);
      ((ushort4*)out)[i] = o;
    }
  };
  if (b < 2048) {
    cvt_seg(x, x_bf, b * 256 + threadIdx.x, 8192 * 2048 / 4, 2048 * 256);
  } else if (b < 2048 + 768) {
    cvt_seg(wq, wq_bf, (b - 2048) * 256 + threadIdx.x, 6144 * 2048 / 4, 768 * 256);
  } else if (b < 2048 + 768 + 256) {
    cvt_seg(wo, wo_bf, (b - 2816) * 256 + threadIdx.x, 2048 * 2048 / 4, 256 * 256);
  } else {
    const int i = (b - 3072) * 256 + threadIdx.x;
    if (i < 131072) {
      float f = freqs[i];
      cst[i] = make_float2(cosf(f), sinf(f));
    }
  }
}

// ---------------- GEMM: C[M][N] = A[M][K] * B[N][K]^T (both K-major bf16) ----------------
// 256x256 tile, BK=32, 8 waves (2M x 4N), ring-of-4 LDS pipeline, counted vmcnt, R6/R8-proven
// phase rhythm. MODE 0: float C out. MODE 2: fused RoPE epilogue -> q_r/k_r [BH][T][128]
// (Q pre-scaled by 1/sqrt(128)*log2e) and V transposed DIRECTLY to vt [BH][128][T] via LDS.
// (R14/R16-exact hot kernel.)
template <int MODE>
__global__ __launch_bounds__(512, 2) void gemm_bt(const u16* __restrict__ A,
                                                  const u16* __restrict__ Bm,
                                                  void* __restrict__ Cp,
                                                  u16* __restrict__ q_r,
                                                  u16* __restrict__ k_r,
                                                  u16* __restrict__ v_t,
                                                  const float2* __restrict__ cst,
                                                  const int M, const int N, const int K) {
  // flattened LDS: As[slot] = SH + slot*8192 (u16), Bs[slot] = SH + 32768 + slot*8192.
  // 4 slots x (256x32) x 2 matrices = 128 KB. Reused by the V-transpose epilogue.
  __shared__ __align__(16) u16 SH[65536];
  const int tid = threadIdx.x;
  const int wid = tid >> 6;      // 0..7
  const int lane = tid & 63;
  const int lrow = lane & 15;
  const int lgrp = lane >> 4;

  // T1: XCD-aware bijective block swizzle (nwg % 8 == 0 in all our launches)
  const int gx = gridDim.x;
  const int nwg = gx * gridDim.y;
  int id = blockIdx.y * gx + blockIdx.x;
  const int cpx = nwg >> 3;
  id = (id & 7) * cpx + (id >> 3);
  const int row0 = (id / gx) * 256;
  const int col0 = (id % gx) * 256;

  const int wm = (wid >> 2) * 128;   // wave M-offset (2 rows of waves)
  const int wn = (wid & 3) * 64;     // wave N-offset (4 cols of waves)

  f32x4 acc[8][4] = {};

  // staging geometry: wave-instruction j covers LDS rows j*16..j*16+15 (64B/row, 4 chunks)
  const int sj0 = wid * 2;
  const int srow = lane >> 2;   // + j*16
  const int sc = lane & 3;

// one half-stage: 2 gload_lds (1 A + 1 B), inverse-swizzled global source (rule 21)
#define STAGE_HALF(SLOT, T, II)                                                   \
  do {                                                                            \
    const int j_ = sj0 + (II);                                                    \
    const int row_ = j_ * 16 + srow;                                              \
    const int ch_ = sc ^ ((row_ >> 1) & 3);                                       \
    const int k0_ = (T) * 32;                                                     \
    gload_lds16(A + (size_t)(row0 + row_) * K + k0_ + ch_ * 8,                    \
                (char*)SH + (SLOT) * 16384 + j_ * 1024);                          \
    gload_lds16(Bm + (size_t)(col0 + row_) * K + k0_ + ch_ * 8,                   \
                (char*)SH + 65536 + (SLOT) * 16384 + j_ * 1024);                  \
  } while (0)

#define READS_B(SLOT)                                                             \
  _Pragma("unroll") for (int fn = 0; fn < 4; ++fn) {                              \
    const int brow_ = wn + fn * 16 + lrow;                                        \
    bfr[fn] = *(const bf16x8*)((const char*)SH + 65536 + (SLOT) * 16384 +         \
                               brow_ * 64 + ((lgrp ^ ((brow_ >> 1) & 3)) << 4));  \
  }

#define READS_A(SLOT, QUAD)                                                       \
  _Pragma("unroll") for (int i_ = 0; i_ < 4; ++i_) {                              \
    const int arow_ = wm + ((QUAD) * 4 + i_) * 16 + lrow;                         \
    af[i_] = *(const bf16x8*)((const char*)SH + (SLOT) * 16384 +                  \
                              arow_ * 64 + ((lgrp ^ ((arow_ >> 1) & 3)) << 4));   \
  }

#define MFMA_QUAD(QUAD)                                                           \
  __builtin_amdgcn_s_setprio(1);                                                  \
  _Pragma("unroll") for (int fm = 0; fm < 4; ++fm) {                              \
    _Pragma("unroll") for (int fn = 0; fn < 4; ++fn)                              \
      acc[(QUAD) * 4 + fm][fn] = MFMA16(af[fm], bfr[fn], acc[(QUAD) * 4 + fm][fn]); \
  }                                                                               \
  __builtin_amdgcn_s_setprio(0);

  const int nk = K >> 5;   // 64 for K=2048
  STAGE_HALF(0, 0, 0); STAGE_HALF(0, 0, 1);
  STAGE_HALF(1, 1, 0); STAGE_HALF(1, 1, 1);
  STAGE_HALF(2, 2, 0); STAGE_HALF(2, 2, 1);   // 12 loads/wave outstanding
  __builtin_amdgcn_sched_barrier(0);
  asm volatile("s_waitcnt vmcnt(8)" ::: "memory");   // tile 0 landed
  __builtin_amdgcn_s_barrier();                      // publish tile 0

  bf16x8 bfr[4], af[4];
  for (int t = 0; t < nk - 2; ++t) {
    const int slot = t & 3;
    const int ns = (t + 3) & 3;
    const bool dostage = (t + 3) < nk;
    // ---- phase A: B-frags + A-quad0 reads, half-stage, MFMA quad0 ----
    READS_B(slot)
    READS_A(slot, 0)
    if (dostage) STAGE_HALF(ns, t + 3, 0);
    __builtin_amdgcn_sched_barrier(0);
    __builtin_amdgcn_s_barrier();
    MFMA_QUAD(0)
    __builtin_amdgcn_sched_barrier(0);
    __builtin_amdgcn_s_barrier();
    // ---- phase B: A-quad1 reads, half-stage, MFMA quad1 ----
    READS_A(slot, 1)
    if (dostage) STAGE_HALF(ns, t + 3, 1);
    __builtin_amdgcn_sched_barrier(0);
    __builtin_amdgcn_s_barrier();
    MFMA_QUAD(1)
    __builtin_amdgcn_sched_barrier(0);
    // ---- publish tile t+1 for next iteration (counted vmcnt, never 0 here) ----
    asm volatile("s_waitcnt vmcnt(8)" ::: "memory");
    __builtin_amdgcn_s_barrier();
  }
  // ---- tail tile nk-2 (published above); nk-1's loads still in flight ----
  {
    const int slot = (nk - 2) & 3;
    READS_B(slot) READS_A(slot, 0)
    __builtin_amdgcn_sched_barrier(0);
    __builtin_amdgcn_s_barrier();
    MFMA_QUAD(0)
    __builtin_amdgcn_s_barrier();
    READS_A(slot, 1)
    __builtin_amdgcn_sched_barrier(0);
    __builtin_amdgcn_s_barrier();
    MFMA_QUAD(1)
    __builtin_amdgcn_sched_barrier(0);
    asm volatile("s_waitcnt vmcnt(0)" ::: "memory");
    __builtin_amdgcn_s_barrier();   // publish tile nk-1
  }
  {
    const int slot = (nk - 1) & 3;
    READS_B(slot) READS_A(slot, 0)
    __builtin_amdgcn_sched_barrier(0);
    __builtin_amdgcn_s_barrier();
    MFMA_QUAD(0)
    __builtin_amdgcn_s_barrier();
    READS_A(slot, 1)
    MFMA_QUAD(1)
  }

  // ---- epilogue: D frag mapping row=lgrp*4+r, col=lrow (verified round 1) ----
  if constexpr (MODE == 0) {
    #pragma unroll
    for (int fm = 0; fm < 8; ++fm) {
      #pragma unroll
      for (int r = 0; r < 4; ++r) {
        const size_t rb = (size_t)(row0 + wm + fm * 16 + lgrp * 4 + r) * N + col0 + wn + lrow;
        #pragma unroll
        for (int fn = 0; fn < 4; ++fn)
          ((float*)Cp)[rb + fn * 16] = acc[fm][fn][r];
      }
    }
  } else {
    const int which = col0 >> 11;            // 0=q, 1=k, 2=v (tile never crosses: 2048%256==0)
    if (which < 2) {
      // fused RoPE + rearrange: col -> (h, d); write q_r/k_r (rope'd).
      // RoPE pair (2i,2i+1) = adjacent lanes (col=lrow); exchange via shfl_xor(.,1).
      // Q additionally scaled by (1/sqrt(128))*log2(e) -- folded softmax scale.
      const int colw = (col0 & 2047) + wn;     // within-which wave col base
      const int h = colw >> 7;                 // head (64-wide wave range never crosses head)
      const int d0 = colw & 127;               // 0 or 64
      u16* const dst0 = (which == 0) ? q_r : k_r;
      const float wscale = (which == 0) ? (0.08838834765f * 1.44269504089f) : 1.0f;
      #pragma unroll
      for (int fm = 0; fm < 8; ++fm) {
        #pragma unroll
        for (int r = 0; r < 4; ++r) {
          const int grow = row0 + wm + fm * 16 + lgrp * 4 + r;
          const int bb = grow >> 11, tt = grow & 2047;
          u16* const drow = dst0 + (((size_t)(bb * 16 + h) * 2048 + tt) << 7);
          #pragma unroll
          for (int fn = 0; fn < 4; ++fn) {
            const float v = acc[fm][fn][r];
            const float p = __shfl_xor(v, 1);
            const int d = d0 + fn * 16 + lrow;
            const float2 cs = cst[tt * 64 + (d >> 1)];
            const float o = ((lrow & 1) ? (p * cs.y + v * cs.x) : (v * cs.x - p * cs.y)) * wscale;
            drow[d] = f2bf(o);
          }
        }
      }
    } else {
      // V tile: transpose through LDS, write vt[bh][d][t] directly (coalesced 16B stores).
      // Two 128-row chunks; pitch 260 keeps both LDS phases ~conflict-free.
      const int hbase = (col0 - 4096) >> 7;   // first head of this tile
      const int bb = row0 >> 11;
      const int tloc0 = row0 & 2047;
      const int hd = tid >> 1, half = tid & 1;           // hd = column 0..255
      const int hh = hd >> 7, dd = hd & 127;
      u16* const dstb = v_t + ((size_t)(bb * 16 + hbase + hh) * 128 + dd) * 2048;
      #pragma unroll
      for (int c = 0; c < 2; ++c) {
        __builtin_amdgcn_s_barrier();   // K-loop reads / prev chunk reads retired
        if ((wm >> 7) == c) {           // waves owning rows c*128..c*128+127
          #pragma unroll
          for (int fm = 0; fm < 8; ++fm) {
            #pragma unroll
            for (int r = 0; r < 4; ++r) {
              const int rl = fm * 16 + lgrp * 4 + r;   // 0..127 local row
              #pragma unroll
              for (int fn = 0; fn < 4; ++fn)
                SH[rl * 260 + wn + fn * 16 + lrow] = f2bf(acc[fm][fn][r]);
            }
          }
        }
        __builtin_amdgcn_s_barrier();
        u16* dst = dstb + tloc0 + c * 128 + half * 64;
        #pragma unroll
        for (int seg = 0; seg < 8; ++seg) {
          const int tb = (half * 64 + seg * 8) * 260 + hd;
          u32 w0 = (u32)SH[tb]        | ((u32)SH[tb + 260] << 16);
          u32 w1 = (u32)SH[tb + 520]  | ((u32)SH[tb + 780] << 16);
          u32 w2 = (u32)SH[tb + 1040] | ((u32)SH[tb + 1300] << 16);
          u32 w3 = (u32)SH[tb + 1560] | ((u32)SH[tb + 1820] << 16);
          uint4 w = make_uint4(w0, w1, w2, w3);
          *(uint4*)(dst + seg * 8) = w;
        }
      }
    }
  }
#undef STAGE_HALF
#undef READS_B
#undef READS_A
#undef MFMA_QUAD
}

// ---------------- Flash attention (causal), Q-tile 256, 8 waves x 32 q-rows, KVBLK=64.
// Uniform-work pairing (36 tile-iters/block, 256 blocks = 1/CU). Ring-of-4 KV pipeline,
// counted vmcnt. T15 double-pipeline: QK(j+1) MFMAs issued at iter j so softmax(j)'s VALU
// overlaps them (mask moved into softmax phase; static sA/sB states, 2-unrolled loop).
// Merged qg softmax/PV chains. Scale folded into Q. Same-XCD bh grouping. ----------------
__global__ __launch_bounds__(512, 2) void attn_fwd(const u16* __restrict__ Qp,
                                                   const u16* __restrict__ Kp,
                                                   const u16* __restrict__ Vp,
                                                   u16* __restrict__ Op) {
  constexpr int T = 2048;
  __shared__ __align__(16) u16 Kl[4][64 * 128];   // [kv][d], XOR-swizzled 16B chunks
  __shared__ __align__(16) u16 Vl[4][128 * 64];   // [d][kv], XOR-swizzled 16B chunks
  __shared__ __align__(16) u16 Pl[8 * 2048];      // per-wave 4KB (2 qg strips), swizzled

  const int tid = threadIdx.x;
  const int wid = tid >> 6;      // 0..7
  const int lane = tid & 63;
  const int lrow = lane & 15;
  const int lgrp = lane >> 4;

  // uniform-work pairing + same-XCD bh grouping (blocks sharing bh -> same lin%8 -> same XCD)
  const int lin = blockIdx.y * 4 + blockIdx.x;           // 0..255
  const int qa = lin >> 6;                               // 0..3
  const int bh = ((lin & 7) << 3) | ((lin >> 3) & 7);    // bijective in lin&63

  const u16* Qb = Qp + (size_t)bh * T * 128;
  const u16* Kb = Kp + (size_t)bh * T * 128;
  const u16* Vb = Vp + (size_t)bh * 128 * T;

  const float DTH = 12.0f;                           // defer-max threshold (exp2 domain)
  const int s0 = (lane & 48) + ((lane & 48) >> 2);   // shfl src base: lane(lgrp, lrow=lgrp*4)
  char* Pw = (char*)Pl + wid * 4096;
  const int ob = bh >> 4, oh = bh & 15;

  auto stage = [&](int buf, int kv0) {
    #pragma unroll
    for (int ii = 0; ii < 2; ++ii) {
      const int i = wid * 2 + ii;  // 0..15
      {
        const int rr = i * 4 + (lane >> 4);
        const int cs = (lane & 15) ^ (rr & 7);
        gload_lds16(Kb + (size_t)(kv0 + rr) * 128 + cs * 8, (char*)&Kl[buf][0] + i * 1024);
      }
      {
        const int rr = i * 8 + (lane >> 3);
        const int cs = (lane & 7) ^ (rr & 7);
        gload_lds16(Vb + (size_t)rr * T + kv0 + cs * 8, (char*)&Vl[buf][0] + i * 1024);
      }
    }
  };

  auto process = [&](const int qi) {
    const int q0 = qi * 256;
    const int wq0 = q0 + wid * 32;   // this wave's first q-row

    // Q fragments: 2 q-groups x 16 rows; lane holds Q[q = wq0 + qg*16 + lrow][d-chunk]
    bf16x8 qf[2][4];
    #pragma unroll
    for (int qg = 0; qg < 2; ++qg) {
      const int qrow = wq0 + qg * 16 + lrow;
      #pragma unroll
      for (int db = 0; db < 4; ++db)
        qf[qg][db] = *(const bf16x8*)(Qb + (size_t)qrow * 128 + db * 32 + lgrp * 8);
    }

    f32x4 o[2][8] = {};
    float m[2] = {-3e38f, -3e38f};
    float l[2] = {0.f, 0.f};

    // QK for tile j into s (pure MFMA issue; no consumption of results here)
    auto qk = [&](int j, f32x4 (&s)[2][4]) {
      const int kv0 = j * 64;
      if (kv0 > wq0 + 31) return;
      const int csl = j & 3;
      #pragma unroll
      for (int qg = 0; qg < 2; ++qg)
        #pragma unroll
        for (int t4 = 0; t4 < 4; ++t4) s[qg][t4] = f32x4{0.f, 0.f, 0.f, 0.f};
      __builtin_amdgcn_s_setprio(1);
      #pragma unroll
      for (int t4 = 0; t4 < 4; ++t4) {
        const int krow = t4 * 16 + lrow;
        #pragma unroll
        for (int db = 0; db < 4; ++db) {
          const int ch = (db * 4 + lgrp) ^ (krow & 7);
          bf16x8 kf = *(const bf16x8*)((const char*)&Kl[csl][0] + krow * 256 + ch * 16);
          s[0][t4] = MFMA16(kf, qf[0][db], s[0][t4]);
          s[1][t4] = MFMA16(kf, qf[1][db], s[1][t4]);
        }
      }
      __builtin_amdgcn_s_setprio(0);
    };

    // mask + softmax + PV for tile j (consumes s computed >= 1 iter earlier)
    auto smpv = [&](int j, f32x4 (&s)[2][4]) {
      const int kv0 = j * 64;
      if (kv0 > wq0 + 31) return;
      const int csl = j & 3;

      // --- causal mask: k_local = t4*16 + lgrp*4 + r; mask if kv0 + k_local > q ---
      if (kv0 + 63 > wq0) {
        #pragma unroll
        for (int qg = 0; qg < 2; ++qg) {
          const int lim = wq0 + qg * 16 + lrow - kv0 - lgrp * 4;
          #pragma unroll
          for (int t4 = 0; t4 < 4; ++t4) {
            #pragma unroll
            for (int r = 0; r < 4; ++r)
              if (t4 * 16 + r > lim) s[qg][t4][r] = -3e38f;
          }
        }
      }

      // --- row max: 16 in-lane values + 2 shfl rounds (over lgrp) ---
      float pmax[2];
      #pragma unroll
      for (int qg = 0; qg < 2; ++qg) {
        float pm = fmaxf(fmaxf(s[qg][0][0], s[qg][0][1]), fmaxf(s[qg][0][2], s[qg][0][3]));
        #pragma unroll
        for (int t4 = 1; t4 < 4; ++t4)
          pm = fmaxf(pm, fmaxf(fmaxf(s[qg][t4][0], s[qg][t4][1]),
                               fmaxf(s[qg][t4][2], s[qg][t4][3])));
        pm = fmaxf(pm, __shfl_xor(pm, 16));
        pm = fmaxf(pm, __shfl_xor(pm, 32));
        pmax[qg] = pm;
      }

      // --- defer-max: rescale only if max grew past threshold (wave-uniform branch) ---
      float alpha[2] = {1.f, 1.f};
      const float dmax = fmaxf(pmax[0] - m[0], pmax[1] - m[1]);
      if (__any(dmax > DTH)) {
        #pragma unroll
        for (int qg = 0; qg < 2; ++qg) {
          const float mn = fmaxf(m[qg], pmax[qg]);
          alpha[qg] = exp2f(m[qg] - mn);
          m[qg] = mn;
        }
        #pragma unroll
        for (int qg = 0; qg < 2; ++qg) {
          #pragma unroll
          for (int r = 0; r < 4; ++r) {
            const float a4 = __shfl(alpha[qg], s0 + r);  // alpha of q_local = lgrp*4+r
            #pragma unroll
            for (int db = 0; db < 8; ++db)
              o[qg][db][r] *= a4;
          }
        }
      }

      // --- exp + row-sum, both q-groups (scale pre-folded into Q) ---
      float psum[2] = {0.f, 0.f};
      #pragma unroll
      for (int qg = 0; qg < 2; ++qg) {
        #pragma unroll
        for (int t4 = 0; t4 < 4; ++t4) {
          #pragma unroll
          for (int r = 0; r < 4; ++r) {
            const float p = exp2f(s[qg][t4][r] - m[qg]);
            s[qg][t4][r] = p;
            psum[qg] += p;
          }
        }
        psum[qg] += __shfl_xor(psum[qg], 16);
        psum[qg] += __shfl_xor(psum[qg], 32);
        l[qg] = l[qg] * alpha[qg] + psum[qg];
      }

      // --- pack P for BOTH q-groups -> per-qg strips, then ONE lgkm wait ---
      #pragma unroll
      for (int qg = 0; qg < 2; ++qg) {
        #pragma unroll
        for (int t4 = 0; t4 < 4; ++t4) {
          uint2 w;
          w.x = (u32)f2bf(s[qg][t4][0]) | ((u32)f2bf(s[qg][t4][1]) << 16);
          w.y = (u32)f2bf(s[qg][t4][2]) | ((u32)f2bf(s[qg][t4][3]) << 16);
          const int off = lrow * 128 + (((t4 * 2 + (lgrp >> 1)) ^ (lrow & 7)) << 4) + (lgrp & 1) * 8;
          *(uint2*)(Pw + qg * 2048 + off) = w;
        }
      }
      asm volatile("s_waitcnt lgkmcnt(0)" ::: "memory");
      __builtin_amdgcn_sched_barrier(0);

      // --- PV: one 32-MFMA cluster, V fragments shared across q-groups ---
      bf16x8 pa[2][2];
      #pragma unroll
      for (int qg = 0; qg < 2; ++qg) {
        #pragma unroll
        for (int kb = 0; kb < 2; ++kb)
          pa[qg][kb] = *(const bf16x8*)(Pw + qg * 2048 + lrow * 128 +
                                        (((kb * 4 + lgrp) ^ (lrow & 7)) << 4));
      }
      __builtin_amdgcn_s_setprio(1);
      #pragma unroll
      for (int db = 0; db < 8; ++db) {
        const int vrow = db * 16 + lrow;
        #pragma unroll
        for (int kb = 0; kb < 2; ++kb) {
          const int vch = (kb * 4 + lgrp) ^ (vrow & 7);
          bf16x8 vf = *(const bf16x8*)((const char*)&Vl[csl][0] + vrow * 128 + vch * 16);
          o[0][db] = MFMA16(pa[0][kb], vf, o[0][db]);
          o[1][db] = MFMA16(pa[1][kb], vf, o[1][db]);
        }
      }
      __builtin_amdgcn_s_setprio(0);
    };

    const int nkv = 4 * qi + 4;   // always even, >= 4
    f32x4 sA[2][4], sB[2][4];

    stage(0, 0);
    stage(1, 64);
    stage(2, 128);                                     // 12 loads/wave outstanding
    asm volatile("s_waitcnt vmcnt(4)" ::: "memory");   // retire tiles 0,1
    __builtin_amdgcn_s_barrier();                      // publish tiles 0,1
    qk(0, sA);

    for (int j = 0; j < nkv; j += 2) {
      // ---- body(j): uses sA, prefetches QK(j+1) into sB ----
      if (j + 3 < nkv) stage((j + 3) & 3, (j + 3) * 64);   // slot (j-1)&3, readers done
      if (j + 1 < nkv) qk(j + 1, sB);                      // tile j+1 published last iter
      smpv(j, sA);
      if (j + 3 < nkv) asm volatile("s_waitcnt vmcnt(4)" ::: "memory");  // retire j+2
      else             asm volatile("s_waitcnt vmcnt(0)" ::: "memory");
      __builtin_amdgcn_s_barrier();                        // publish tile j+2
      // ---- body(j+1): uses sB, prefetches QK(j+2) into sA ----
      if (j + 4 < nkv) stage((j + 4) & 3, (j + 4) * 64);
      if (j + 2 < nkv) qk(j + 2, sA);
      smpv(j + 1, sB);
      if (j + 4 < nkv) asm volatile("s_waitcnt vmcnt(4)" ::: "memory");
      else             asm volatile("s_waitcnt vmcnt(0)" ::: "memory");
      __builtin_amdgcn_s_barrier();
    }

    // --- epilogue: normalize and store ---
    #pragma unroll
    for (int qg = 0; qg < 2; ++qg) {
      const float inv = 1.f / l[qg];
      float inv4[4];
      #pragma unroll
      for (int r = 0; r < 4; ++r) inv4[r] = __shfl(inv, s0 + r);
      #pragma unroll
      for (int db = 0; db < 8; ++db) {
        #pragma unroll
        for (int r = 0; r < 4; ++r) {
          const int qrow = wq0 + qg * 16 + lgrp * 4 + r;
          Op[((size_t)ob * T + qrow) * 2048 + oh * 128 + db * 16 + lrow] =
              f2bf(o[qg][db][r] * inv4[r]);
        }
      }
    }
  };

  process(7 - qa);     // heavy Q-tile
  __syncthreads();     // all waves done reading KV slots before pass-2 staging
  process(qa);         // light Q-tile -> every block totals exactly 36 tile-iters
}

// ---------------- host launcher ----------------
extern "C" void kernel_launch(void* const* d_in, const int* in_sizes, int n_in,
                              void* d_out, int out_size, void* d_ws, size_t ws_size,
                              hipStream_t stream) {
  const float* x = (const float*)d_in[0];
  const float* freqs = (const float*)d_in[1];
  const float* w_qkv = (const float*)d_in[2];
  const float* w_o = (const float*)d_in[3];

  constexpr int B = 4, T = 2048, E = 2048, H = 16;
  constexpr size_t M = (size_t)B * T;  // 8192
  constexpr int N3 = 3 * E;            // 6144

  char* ws = (char*)d_ws;
  size_t off = 0;
  auto alloc = [&](size_t bytes) {
    void* p = ws + off;
    off += (bytes + 255) & ~(size_t)255;
    return p;
  };
  u16* wqkv_bf = (u16*)alloc((size_t)N3 * E * 2);   // 25.2 MB
  u16* wo_bf   = (u16*)alloc((size_t)E * E * 2);    //  8.4 MB
  u16* x_bf    = (u16*)alloc(M * E * 2);            // 33.6 MB
  u16* q_r     = (u16*)alloc(M * E * 2);            // 33.6 MB
  u16* k_r     = (u16*)alloc(M * E * 2);            // 33.6 MB
  u16* vt      = (u16*)alloc(M * E * 2);            // 33.6 MB
  u16* attn_o  = (u16*)alloc(M * E * 2);            // 33.6 MB
  float2* cst  = (float2*)alloc((size_t)T * 64 * 8);// 1 MB

  prologue<<<3584, 256, 0, stream>>>(x, w_qkv, w_o, freqs, x_bf, wqkv_bf, wo_bf, cst);

  // QKV GEMM with fused RoPE + rearrange epilogue (Q pre-scaled) + direct V-transpose to vt
  gemm_bt<2><<<dim3(N3 / 256, (int)(M / 256)), 512, 0, stream>>>(
      x_bf, wqkv_bf, nullptr, q_r, k_r, vt, cst, (int)M, N3, E);
  attn_fwd<<<dim3(4, B * H), 512, 0, stream>>>(q_r, k_r, vt, attn_o);
  gemm_bt<0><<<dim3(E / 256, (int)(M / 256)), 512, 0, stream>>>(
      attn_o, wo_bf, d_out, nullptr, nullptr, nullptr, nullptr, (int)M, E, E);
}

// Round 18
// 432.559 us; speedup vs baseline: 1.0134x; 1.0134x over previous
//
#include <hip/hip_runtime.h>
#include <type_traits>

#define DEV __device__ __forceinline__

typedef __attribute__((ext_vector_type(4))) float f32x4;
typedef __attribute__((ext_vector_type(8))) __bf16 bf16x8;
typedef __attribute__((ext_vector_type(8))) short s16x8;
typedef unsigned int u32;
typedef unsigned short u16;

DEV u16 f2bf(float f) {
  u32 u = __builtin_bit_cast(u32, f);
  u32 r = u + 0x7FFFu + ((u >> 16) & 1u);
  return (u16)(r >> 16);
}
DEV float bf2f(u16 h) {
  u32 u = ((u32)h) << 16;
  return __builtin_bit_cast(float, u);
}

// ---- MFMA wrapper: SFINAE over builtin operand type (bf16x8 vs s16x8) ----
template <typename A>
DEV auto mfma_sel(A a, A b, f32x4 c, int)
    -> decltype(__builtin_amdgcn_mfma_f32_16x16x32_bf16(a, b, c, 0, 0, 0)) {
  return __builtin_amdgcn_mfma_f32_16x16x32_bf16(a, b, c, 0, 0, 0);
}
template <typename A>
DEV f32x4 mfma_sel(A a, A b, f32x4 c, long) {
  using O = typename std::conditional<std::is_same<A, bf16x8>::value, s16x8, bf16x8>::type;
  return __builtin_amdgcn_mfma_f32_16x16x32_bf16(
      __builtin_bit_cast(O, a), __builtin_bit_cast(O, b), c, 0, 0, 0);
}
DEV f32x4 MFMA16(bf16x8 a, bf16x8 b, f32x4 c) { return mfma_sel(a, b, c, 0); }

DEV void gload_lds16(const void* g, void* l) {
  __builtin_amdgcn_global_load_lds(
      (__attribute__((address_space(1))) void*)(g),
      (__attribute__((address_space(3))) void*)(l), 16, 0, 0);
}

// ---------------- fused prologue: cvt x / w_qkv / w_o to bf16 + cos/sin table ----------------
// grid = 2048 (x) + 768 (w_qkv) + 256 (w_o) + 512 (cst) = 3584 blocks x 256 threads.
__global__ __launch_bounds__(256) void prologue(const float* __restrict__ x,
                                                const float* __restrict__ wq,
                                                const float* __restrict__ wo,
                                                const float* __restrict__ freqs,
                                                u16* __restrict__ x_bf,
                                                u16* __restrict__ wq_bf,
                                                u16* __restrict__ wo_bf,
                                                float2* __restrict__ cst) {
  const int b = blockIdx.x;
  auto cvt_seg = [&](const float* in, u16* out, int i, int n4, int stride) {
    for (; i < n4; i += stride) {
      const float4 v = ((const float4*)in)[i];
      ushort4 o;
      o.x = f2bf(v.x); o.y = f2bf(v.y); o.z = f2bf(v.z); o.w = f2bf(v.w);
      ((ushort4*)out)[i] = o;
    }
  };
  if (b < 2048) {
    cvt_seg(x, x_bf, b * 256 + threadIdx.x, 8192 * 2048 / 4, 2048 * 256);
  } else if (b < 2048 + 768) {
    cvt_seg(wq, wq_bf, (b - 2048) * 256 + threadIdx.x, 6144 * 2048 / 4, 768 * 256);
  } else if (b < 2048 + 768 + 256) {
    cvt_seg(wo, wo_bf, (b - 2816) * 256 + threadIdx.x, 2048 * 2048 / 4, 256 * 256);
  } else {
    const int i = (b - 3072) * 256 + threadIdx.x;
    if (i < 131072) {
      float f = freqs[i];
      cst[i] = make_float2(cosf(f), sinf(f));
    }
  }
}

// ---------------- GEMM: C[M][N] = A[M][K] * B[N][K]^T (both K-major bf16) ----------------
// 256x256 tile, BK=32, 8 waves (2M x 4N), ring-of-4 LDS pipeline, counted vmcnt, R6/R8-proven
// phase rhythm. MODE 0: float C out. MODE 2: fused RoPE epilogue -> q_r/k_r [BH][T][128]
// (Q pre-scaled by 1/sqrt(128)*log2e) and V transposed DIRECTLY to vt [BH][128][T] via LDS.
// (R14/R16-exact hot kernel: the session-best checkpoint.)
template <int MODE>
__global__ __launch_bounds__(512, 2) void gemm_bt(const u16* __restrict__ A,
                                                  const u16* __restrict__ Bm,
                                                  void* __restrict__ Cp,
                                                  u16* __restrict__ q_r,
                                                  u16* __restrict__ k_r,
                                                  u16* __restrict__ v_t,
                                                  const float2* __restrict__ cst,
                                                  const int M, const int N, const int K) {
  // flattened LDS: As[slot] = SH + slot*8192 (u16), Bs[slot] = SH + 32768 + slot*8192.
  // 4 slots x (256x32) x 2 matrices = 128 KB. Reused by the V-transpose epilogue.
  __shared__ __align__(16) u16 SH[65536];
  const int tid = threadIdx.x;
  const int wid = tid >> 6;      // 0..7
  const int lane = tid & 63;
  const int lrow = lane & 15;
  const int lgrp = lane >> 4;

  // T1: XCD-aware bijective block swizzle (nwg % 8 == 0 in all our launches)
  const int gx = gridDim.x;
  const int nwg = gx * gridDim.y;
  int id = blockIdx.y * gx + blockIdx.x;
  const int cpx = nwg >> 3;
  id = (id & 7) * cpx + (id >> 3);
  const int row0 = (id / gx) * 256;
  const int col0 = (id % gx) * 256;

  const int wm = (wid >> 2) * 128;   // wave M-offset (2 rows of waves)
  const int wn = (wid & 3) * 64;     // wave N-offset (4 cols of waves)

  f32x4 acc[8][4] = {};

  // staging geometry: wave-instruction j covers LDS rows j*16..j*16+15 (64B/row, 4 chunks)
  const int sj0 = wid * 2;
  const int srow = lane >> 2;   // + j*16
  const int sc = lane & 3;

// one half-stage: 2 gload_lds (1 A + 1 B), inverse-swizzled global source (rule 21)
#define STAGE_HALF(SLOT, T, II)                                                   \
  do {                                                                            \
    const int j_ = sj0 + (II);                                                    \
    const int row_ = j_ * 16 + srow;                                              \
    const int ch_ = sc ^ ((row_ >> 1) & 3);                                       \
    const int k0_ = (T) * 32;                                                     \
    gload_lds16(A + (size_t)(row0 + row_) * K + k0_ + ch_ * 8,                    \
                (char*)SH + (SLOT) * 16384 + j_ * 1024);                          \
    gload_lds16(Bm + (size_t)(col0 + row_) * K + k0_ + ch_ * 8,                   \
                (char*)SH + 65536 + (SLOT) * 16384 + j_ * 1024);                  \
  } while (0)

#define READS_B(SLOT)                                                             \
  _Pragma("unroll") for (int fn = 0; fn < 4; ++fn) {                              \
    const int brow_ = wn + fn * 16 + lrow;                                        \
    bfr[fn] = *(const bf16x8*)((const char*)SH + 65536 + (SLOT) * 16384 +         \
                               brow_ * 64 + ((lgrp ^ ((brow_ >> 1) & 3)) << 4));  \
  }

#define READS_A(SLOT, QUAD)                                                       \
  _Pragma("unroll") for (int i_ = 0; i_ < 4; ++i_) {                              \
    const int arow_ = wm + ((QUAD) * 4 + i_) * 16 + lrow;                         \
    af[i_] = *(const bf16x8*)((const char*)SH + (SLOT) * 16384 +                  \
                              arow_ * 64 + ((lgrp ^ ((arow_ >> 1) & 3)) << 4));   \
  }

#define MFMA_QUAD(QUAD)                                                           \
  __builtin_amdgcn_s_setprio(1);                                                  \
  _Pragma("unroll") for (int fm = 0; fm < 4; ++fm) {                              \
    _Pragma("unroll") for (int fn = 0; fn < 4; ++fn)                              \
      acc[(QUAD) * 4 + fm][fn] = MFMA16(af[fm], bfr[fn], acc[(QUAD) * 4 + fm][fn]); \
  }                                                                               \
  __builtin_amdgcn_s_setprio(0);

  const int nk = K >> 5;   // 64 for K=2048
  STAGE_HALF(0, 0, 0); STAGE_HALF(0, 0, 1);
  STAGE_HALF(1, 1, 0); STAGE_HALF(1, 1, 1);
  STAGE_HALF(2, 2, 0); STAGE_HALF(2, 2, 1);   // 12 loads/wave outstanding
  __builtin_amdgcn_sched_barrier(0);
  asm volatile("s_waitcnt vmcnt(8)" ::: "memory");   // tile 0 landed
  __builtin_amdgcn_s_barrier();                      // publish tile 0

  bf16x8 bfr[4], af[4];
  for (int t = 0; t < nk - 2; ++t) {
    const int slot = t & 3;
    const int ns = (t + 3) & 3;
    const bool dostage = (t + 3) < nk;
    // ---- phase A: B-frags + A-quad0 reads, half-stage, MFMA quad0 ----
    READS_B(slot)
    READS_A(slot, 0)
    if (dostage) STAGE_HALF(ns, t + 3, 0);
    __builtin_amdgcn_sched_barrier(0);
    __builtin_amdgcn_s_barrier();
    MFMA_QUAD(0)
    __builtin_amdgcn_sched_barrier(0);
    __builtin_amdgcn_s_barrier();
    // ---- phase B: A-quad1 reads, half-stage, MFMA quad1 ----
    READS_A(slot, 1)
    if (dostage) STAGE_HALF(ns, t + 3, 1);
    __builtin_amdgcn_sched_barrier(0);
    __builtin_amdgcn_s_barrier();
    MFMA_QUAD(1)
    __builtin_amdgcn_sched_barrier(0);
    // ---- publish tile t+1 for next iteration (counted vmcnt, never 0 here) ----
    asm volatile("s_waitcnt vmcnt(8)" ::: "memory");
    __builtin_amdgcn_s_barrier();
  }
  // ---- tail tile nk-2 (published above); nk-1's loads still in flight ----
  {
    const int slot = (nk - 2) & 3;
    READS_B(slot) READS_A(slot, 0)
    __builtin_amdgcn_sched_barrier(0);
    __builtin_amdgcn_s_barrier();
    MFMA_QUAD(0)
    __builtin_amdgcn_s_barrier();
    READS_A(slot, 1)
    __builtin_amdgcn_sched_barrier(0);
    __builtin_amdgcn_s_barrier();
    MFMA_QUAD(1)
    __builtin_amdgcn_sched_barrier(0);
    asm volatile("s_waitcnt vmcnt(0)" ::: "memory");
    __builtin_amdgcn_s_barrier();   // publish tile nk-1
  }
  {
    const int slot = (nk - 1) & 3;
    READS_B(slot) READS_A(slot, 0)
    __builtin_amdgcn_sched_barrier(0);
    __builtin_amdgcn_s_barrier();
    MFMA_QUAD(0)
    __builtin_amdgcn_s_barrier();
    READS_A(slot, 1)
    MFMA_QUAD(1)
  }

  // ---- epilogue: D frag mapping row=lgrp*4+r, col=lrow (verified round 1) ----
  if constexpr (MODE == 0) {
    #pragma unroll
    for (int fm = 0; fm < 8; ++fm) {
      #pragma unroll
      for (int r = 0; r < 4; ++r) {
        const size_t rb = (size_t)(row0 + wm + fm * 16 + lgrp * 4 + r) * N + col0 + wn + lrow;
        #pragma unroll
        for (int fn = 0; fn < 4; ++fn)
          ((float*)Cp)[rb + fn * 16] = acc[fm][fn][r];
      }
    }
  } else {
    const int which = col0 >> 11;            // 0=q, 1=k, 2=v (tile never crosses: 2048%256==0)
    if (which < 2) {
      // fused RoPE + rearrange: col -> (h, d); write q_r/k_r (rope'd).
      // RoPE pair (2i,2i+1) = adjacent lanes (col=lrow); exchange via shfl_xor(.,1).
      // Q additionally scaled by (1/sqrt(128))*log2(e) -- folded softmax scale.
      const int colw = (col0 & 2047) + wn;     // within-which wave col base
      const int h = colw >> 7;                 // head (64-wide wave range never crosses head)
      const int d0 = colw & 127;               // 0 or 64
      u16* const dst0 = (which == 0) ? q_r : k_r;
      const float wscale = (which == 0) ? (0.08838834765f * 1.44269504089f) : 1.0f;
      #pragma unroll
      for (int fm = 0; fm < 8; ++fm) {
        #pragma unroll
        for (int r = 0; r < 4; ++r) {
          const int grow = row0 + wm + fm * 16 + lgrp * 4 + r;
          const int bb = grow >> 11, tt = grow & 2047;
          u16* const drow = dst0 + (((size_t)(bb * 16 + h) * 2048 + tt) << 7);
          #pragma unroll
          for (int fn = 0; fn < 4; ++fn) {
            const float v = acc[fm][fn][r];
            const float p = __shfl_xor(v, 1);
            const int d = d0 + fn * 16 + lrow;
            const float2 cs = cst[tt * 64 + (d >> 1)];
            const float o = ((lrow & 1) ? (p * cs.y + v * cs.x) : (v * cs.x - p * cs.y)) * wscale;
            drow[d] = f2bf(o);
          }
        }
      }
    } else {
      // V tile: transpose through LDS, write vt[bh][d][t] directly (coalesced 16B stores).
      // Two 128-row chunks; pitch 260 keeps both LDS phases ~conflict-free.
      const int hbase = (col0 - 4096) >> 7;   // first head of this tile
      const int bb = row0 >> 11;
      const int tloc0 = row0 & 2047;
      const int hd = tid >> 1, half = tid & 1;           // hd = column 0..255
      const int hh = hd >> 7, dd = hd & 127;
      u16* const dstb = v_t + ((size_t)(bb * 16 + hbase + hh) * 128 + dd) * 2048;
      #pragma unroll
      for (int c = 0; c < 2; ++c) {
        __builtin_amdgcn_s_barrier();   // K-loop reads / prev chunk reads retired
        if ((wm >> 7) == c) {           // waves owning rows c*128..c*128+127
          #pragma unroll
          for (int fm = 0; fm < 8; ++fm) {
            #pragma unroll
            for (int r = 0; r < 4; ++r) {
              const int rl = fm * 16 + lgrp * 4 + r;   // 0..127 local row
              #pragma unroll
              for (int fn = 0; fn < 4; ++fn)
                SH[rl * 260 + wn + fn * 16 + lrow] = f2bf(acc[fm][fn][r]);
            }
          }
        }
        __builtin_amdgcn_s_barrier();
        u16* dst = dstb + tloc0 + c * 128 + half * 64;
        #pragma unroll
        for (int seg = 0; seg < 8; ++seg) {
          const int tb = (half * 64 + seg * 8) * 260 + hd;
          u32 w0 = (u32)SH[tb]        | ((u32)SH[tb + 260] << 16);
          u32 w1 = (u32)SH[tb + 520]  | ((u32)SH[tb + 780] << 16);
          u32 w2 = (u32)SH[tb + 1040] | ((u32)SH[tb + 1300] << 16);
          u32 w3 = (u32)SH[tb + 1560] | ((u32)SH[tb + 1820] << 16);
          uint4 w = make_uint4(w0, w1, w2, w3);
          *(uint4*)(dst + seg * 8) = w;
        }
      }
    }
  }
#undef STAGE_HALF
#undef READS_B
#undef READS_A
#undef MFMA_QUAD
}

// ---------------- Flash attention (causal), Q-tile 256, 8 waves x 32 q-rows, KVBLK=64.
// Uniform-work pairing (36 tile-iters/block, 256 blocks = 1/CU). Ring-of-3 KV pipeline with
// counted vmcnt. Merged qg softmax/PV chains: one lgkm wait + one 32-MFMA PV cluster per iter,
// shared V fragments. Scale folded into Q (exp2 direct). Same-XCD bh grouping. ----------------
__global__ __launch_bounds__(512, 2) void attn_fwd(const u16* __restrict__ Qp,
                                                   const u16* __restrict__ Kp,
                                                   const u16* __restrict__ Vp,
                                                   u16* __restrict__ Op) {
  constexpr int T = 2048;
  __shared__ __align__(16) u16 Kl[3][64 * 128];   // [kv][d], XOR-swizzled 16B chunks
  __shared__ __align__(16) u16 Vl[3][128 * 64];   // [d][kv], XOR-swizzled 16B chunks
  __shared__ __align__(16) u16 Pl[8 * 2048];      // per-wave 4KB (2 qg strips), swizzled

  const int tid = threadIdx.x;
  const int wid = tid >> 6;      // 0..7
  const int lane = tid & 63;
  const int lrow = lane & 15;
  const int lgrp = lane >> 4;

  // uniform-work pairing + same-XCD bh grouping (blocks sharing bh -> same lin%8 -> same XCD)
  const int lin = blockIdx.y * 4 + blockIdx.x;           // 0..255
  const int qa = lin >> 6;                               // 0..3
  const int bh = ((lin & 7) << 3) | ((lin >> 3) & 7);    // bijective in lin&63

  const u16* Qb = Qp + (size_t)bh * T * 128;
  const u16* Kb = Kp + (size_t)bh * T * 128;
  const u16* Vb = Vp + (size_t)bh * 128 * T;

  const float DTH = 12.0f;                           // defer-max threshold (exp2 domain)
  const int s0 = (lane & 48) + ((lane & 48) >> 2);   // shfl src base: lane(lgrp, lrow=lgrp*4)
  char* Pw = (char*)Pl + wid * 4096;
  const int ob = bh >> 4, oh = bh & 15;

  auto stage = [&](int buf, int kv0) {
    #pragma unroll
    for (int ii = 0; ii < 2; ++ii) {
      const int i = wid * 2 + ii;  // 0..15
      {
        const int rr = i * 4 + (lane >> 4);
        const int cs = (lane & 15) ^ (rr & 7);
        gload_lds16(Kb + (size_t)(kv0 + rr) * 128 + cs * 8, (char*)&Kl[buf][0] + i * 1024);
      }
      {
        const int rr = i * 8 + (lane >> 3);
        const int cs = (lane & 7) ^ (rr & 7);
        gload_lds16(Vb + (size_t)rr * T + kv0 + cs * 8, (char*)&Vl[buf][0] + i * 1024);
      }
    }
  };

  auto process = [&](const int qi) {
    const int q0 = qi * 256;
    const int wq0 = q0 + wid * 32;   // this wave's first q-row

    // Q fragments: 2 q-groups x 16 rows; lane holds Q[q = wq0 + qg*16 + lrow][d-chunk]
    bf16x8 qf[2][4];
    #pragma unroll
    for (int qg = 0; qg < 2; ++qg) {
      const int qrow = wq0 + qg * 16 + lrow;
      #pragma unroll
      for (int db = 0; db < 4; ++db)
        qf[qg][db] = *(const bf16x8*)(Qb + (size_t)qrow * 128 + db * 32 + lgrp * 8);
    }

    f32x4 o[2][8] = {};
    float m[2] = {-3e38f, -3e38f};
    float l[2] = {0.f, 0.f};

    const int nkv = 4 * qi + 4;
    stage(0, 0);
    stage(1, 64);    // 8 loads/wave outstanding
    int csl = 0;
    for (int j = 0; j < nkv; ++j) {
      if (j < nkv - 1) asm volatile("s_waitcnt vmcnt(4)" ::: "memory");
      else             asm volatile("s_waitcnt vmcnt(0)" ::: "memory");
      __builtin_amdgcn_s_barrier();   // publish tile j
      if (j + 2 < nkv) {
        int ss = csl + 2; if (ss >= 3) ss -= 3;
        stage(ss, (j + 2) * 64);      // refill slot read at iter j-1
      }
      const int kv0 = j * 64;

      if (kv0 <= wq0 + 31) {  // wave has at least one unmasked q-row for this tile
        // --- QK^T swapped: s[qg][t4][r] = S[k = kv0+t4*16+lgrp*4+r][q = wq0+qg*16+lrow] ---
        f32x4 s[2][4] = {};
        __builtin_amdgcn_s_setprio(1);
        #pragma unroll
        for (int t4 = 0; t4 < 4; ++t4) {
          const int krow = t4 * 16 + lrow;
          #pragma unroll
          for (int db = 0; db < 4; ++db) {
            const int ch = (db * 4 + lgrp) ^ (krow & 7);
            bf16x8 kf = *(const bf16x8*)((const char*)&Kl[csl][0] + krow * 256 + ch * 16);
            s[0][t4] = MFMA16(kf, qf[0][db], s[0][t4]);
            s[1][t4] = MFMA16(kf, qf[1][db], s[1][t4]);
          }
        }
        __builtin_amdgcn_s_setprio(0);

        // --- causal mask: k_local = t4*16 + lgrp*4 + r; mask if kv0 + k_local > q ---
        if (kv0 + 63 > wq0) {
          #pragma unroll
          for (int qg = 0; qg < 2; ++qg) {
            const int lim = wq0 + qg * 16 + lrow - kv0 - lgrp * 4;
            #pragma unroll
            for (int t4 = 0; t4 < 4; ++t4) {
              #pragma unroll
              for (int r = 0; r < 4; ++r)
                if (t4 * 16 + r > lim) s[qg][t4][r] = -3e38f;
            }
          }
        }

        // --- row max: 16 in-lane values + 2 shfl rounds (over lgrp) ---
        float pmax[2];
        #pragma unroll
        for (int qg = 0; qg < 2; ++qg) {
          float pm = fmaxf(fmaxf(s[qg][0][0], s[qg][0][1]), fmaxf(s[qg][0][2], s[qg][0][3]));
          #pragma unroll
          for (int t4 = 1; t4 < 4; ++t4)
            pm = fmaxf(pm, fmaxf(fmaxf(s[qg][t4][0], s[qg][t4][1]),
                                 fmaxf(s[qg][t4][2], s[qg][t4][3])));
          pm = fmaxf(pm, __shfl_xor(pm, 16));
          pm = fmaxf(pm, __shfl_xor(pm, 32));
          pmax[qg] = pm;
        }

        // --- defer-max: rescale only if max grew past threshold (wave-uniform branch) ---
        float alpha[2] = {1.f, 1.f};
        const float dmax = fmaxf(pmax[0] - m[0], pmax[1] - m[1]);
        if (__any(dmax > DTH)) {
          #pragma unroll
          for (int qg = 0; qg < 2; ++qg) {
            const float mn = fmaxf(m[qg], pmax[qg]);
            alpha[qg] = exp2f(m[qg] - mn);
            m[qg] = mn;
          }
          #pragma unroll
          for (int qg = 0; qg < 2; ++qg) {
            #pragma unroll
            for (int r = 0; r < 4; ++r) {
              const float a4 = __shfl(alpha[qg], s0 + r);  // alpha of q_local = lgrp*4+r
              #pragma unroll
              for (int db = 0; db < 8; ++db)
                o[qg][db][r] *= a4;
            }
          }
        }

        // --- exp + row-sum, both q-groups (scale pre-folded into Q) ---
        float psum[2] = {0.f, 0.f};
        #pragma unroll
        for (int qg = 0; qg < 2; ++qg) {
          #pragma unroll
          for (int t4 = 0; t4 < 4; ++t4) {
            #pragma unroll
            for (int r = 0; r < 4; ++r) {
              const float p = exp2f(s[qg][t4][r] - m[qg]);
              s[qg][t4][r] = p;
              psum[qg] += p;
            }
          }
          psum[qg] += __shfl_xor(psum[qg], 16);
          psum[qg] += __shfl_xor(psum[qg], 32);
          l[qg] = l[qg] * alpha[qg] + psum[qg];
        }

        // --- pack P for BOTH q-groups -> per-qg strips, then ONE lgkm wait ---
        #pragma unroll
        for (int qg = 0; qg < 2; ++qg) {
          #pragma unroll
          for (int t4 = 0; t4 < 4; ++t4) {
            uint2 w;
            w.x = (u32)f2bf(s[qg][t4][0]) | ((u32)f2bf(s[qg][t4][1]) << 16);
            w.y = (u32)f2bf(s[qg][t4][2]) | ((u32)f2bf(s[qg][t4][3]) << 16);
            const int off = lrow * 128 + (((t4 * 2 + (lgrp >> 1)) ^ (lrow & 7)) << 4) + (lgrp & 1) * 8;
            *(uint2*)(Pw + qg * 2048 + off) = w;
          }
        }
        asm volatile("s_waitcnt lgkmcnt(0)" ::: "memory");
        __builtin_amdgcn_sched_barrier(0);

        // --- PV: one 32-MFMA cluster, V fragments shared across q-groups ---
        bf16x8 pa[2][2];
        #pragma unroll
        for (int qg = 0; qg < 2; ++qg) {
          #pragma unroll
          for (int kb = 0; kb < 2; ++kb)
            pa[qg][kb] = *(const bf16x8*)(Pw + qg * 2048 + lrow * 128 +
                                          (((kb * 4 + lgrp) ^ (lrow & 7)) << 4));
        }
        __builtin_amdgcn_s_setprio(1);
        #pragma unroll
        for (int db = 0; db < 8; ++db) {
          const int vrow = db * 16 + lrow;
          #pragma unroll
          for (int kb = 0; kb < 2; ++kb) {
            const int vch = (kb * 4 + lgrp) ^ (vrow & 7);
            bf16x8 vf = *(const bf16x8*)((const char*)&Vl[csl][0] + vrow * 128 + vch * 16);
            o[0][db] = MFMA16(pa[0][kb], vf, o[0][db]);
            o[1][db] = MFMA16(pa[1][kb], vf, o[1][db]);
          }
        }
        __builtin_amdgcn_s_setprio(0);
      }
      csl = (csl == 2) ? 0 : csl + 1;
    }

    // --- epilogue: normalize and store ---
    #pragma unroll
    for (int qg = 0; qg < 2; ++qg) {
      const float inv = 1.f / l[qg];
      float inv4[4];
      #pragma unroll
      for (int r = 0; r < 4; ++r) inv4[r] = __shfl(inv, s0 + r);
      #pragma unroll
      for (int db = 0; db < 8; ++db) {
        #pragma unroll
        for (int r = 0; r < 4; ++r) {
          const int qrow = wq0 + qg * 16 + lgrp * 4 + r;
          Op[((size_t)ob * T + qrow) * 2048 + oh * 128 + db * 16 + lrow] =
              f2bf(o[qg][db][r] * inv4[r]);
        }
      }
    }
  };

  process(7 - qa);     // heavy Q-tile
  __syncthreads();     // all waves done reading KV slots before pass-2 staging
  process(qa);         // light Q-tile -> every block totals exactly 36 tile-iters
}

// ---------------- host launcher ----------------
extern "C" void kernel_launch(void* const* d_in, const int* in_sizes, int n_in,
                              void* d_out, int out_size, void* d_ws, size_t ws_size,
                              hipStream_t stream) {
  const float* x = (const float*)d_in[0];
  const float* freqs = (const float*)d_in[1];
  const float* w_qkv = (const float*)d_in[2];
  const float* w_o = (const float*)d_in[3];

  constexpr int B = 4, T = 2048, E = 2048, H = 16;
  constexpr size_t M = (size_t)B * T;  // 8192
  constexpr int N3 = 3 * E;            // 6144

  char* ws = (char*)d_ws;
  size_t off = 0;
  auto alloc = [&](size_t bytes) {
    void* p = ws + off;
    off += (bytes + 255) & ~(size_t)255;
    return p;
  };
  u16* wqkv_bf = (u16*)alloc((size_t)N3 * E * 2);   // 25.2 MB
  u16* wo_bf   = (u16*)alloc((size_t)E * E * 2);    //  8.4 MB
  u16* x_bf    = (u16*)alloc(M * E * 2);            // 33.6 MB
  u16* q_r     = (u16*)alloc(M * E * 2);            // 33.6 MB
  u16* k_r     = (u16*)alloc(M * E * 2);            // 33.6 MB
  u16* vt      = (u16*)alloc(M * E * 2);            // 33.6 MB
  u16* attn_o  = (u16*)alloc(M * E * 2);            // 33.6 MB
  float2* cst  = (float2*)alloc((size_t)T * 64 * 8);// 1 MB

  prologue<<<3584, 256, 0, stream>>>(x, w_qkv, w_o, freqs, x_bf, wqkv_bf, wo_bf, cst);

  // QKV GEMM with fused RoPE + rearrange epilogue (Q pre-scaled) + direct V-transpose to vt
  gemm_bt<2><<<dim3(N3 / 256, (int)(M / 256)), 512, 0, stream>>>(
      x_bf, wqkv_bf, nullptr, q_r, k_r, vt, cst, (int)M, N3, E);
  attn_fwd<<<dim3(4, B * H), 512, 0, stream>>>(q_r, k_r, vt, attn_o);
  gemm_bt<0><<<dim3(E / 256, (int)(M / 256)), 512, 0, stream>>>(
      attn_o, wo_bf, d_out, nullptr, nullptr, nullptr, nullptr, (int)M, E, E);
}